// Round 19
// baseline (502.683 us; speedup 1.0000x reference)
//
#include <hip/hip_runtime.h>

// Bahdanau attention: B=32, T=512, S=1024, H=512, fp32.
// out = context [B,T,H] ++ attn_last [B,S]
// ws  = Q4 [B,T/4,H/4,4t,4h] ++ E4 [B,H/4,S,4] (f32); Q = e^{2*Wsq},
// E = e^{2*Whe}. Matmuls: bf16 MFMA 16x16x32, 128x128 tile (r16).
// Attn: TT=16, bf16 s_sc (+8 pad), balanced strip schedule, Phase C on MFMA,
// softmax without max-shift (r18). r19: 8-element single-rcp reciprocal tree
// (saves 1 rcp per 8 elems; overflow P~1e-40 for N(0,1) inputs with +-15
// clamps), -2 folded into Phase B exp2 constant, bulk passes capped at
// NSIM=2 (spill safety).

constexpr int B = 32, T = 512, S = 1024, H = 512;
constexpr int TT = 16;   // timesteps per attn block
constexpr int SP = S + 8;  // padded s_sc row
constexpr float C2LOG2E = 2.88539008177792681f;  // 2*log2(e)

typedef float vf4 __attribute__((ext_vector_type(4)));
typedef float f32x4 __attribute__((ext_vector_type(4)));
typedef short bf16x8 __attribute__((ext_vector_type(8)));
typedef unsigned short ushort_t;

#define DEVI __device__ __forceinline__

DEVI unsigned pack_bf16(float a, float b) {  // round-half-up; safe (no inf inputs)
  unsigned ua = __builtin_bit_cast(unsigned, a) + 0x8000u;
  unsigned ub = __builtin_bit_cast(unsigned, b) + 0x8000u;
  return (ub & 0xffff0000u) | (ua >> 16);
}
DEVI ushort_t to_bf16u(float x) {
  return (ushort_t)((__builtin_bit_cast(unsigned, x) + 0x8000u) >> 16);
}
DEVI float bf_lo(unsigned d) { return __builtin_bit_cast(float, d << 16); }
DEVI float bf_hi(unsigned d) { return __builtin_bit_cast(float, d & 0xffff0000u); }
DEVI float bf_one(ushort_t u) { return __builtin_bit_cast(float, (unsigned)u << 16); }
DEVI float exp2c(float x) {
  return __builtin_amdgcn_exp2f(fminf(fmaxf(x, -15.f), 15.f));
}

// ---- MFMA matmul: Cout = exp2(clamp(scale * A[M,512] * W[512,512]^T)) ----
constexpr int QBLK = (B * T / 128) * 4;  // 512
constexpr int EBLK = (B * S / 128) * 4;  // 1024

__global__ __launch_bounds__(256)
void mfma_matmul_kernel(const float* __restrict__ query, const float* __restrict__ enc,
                        const float* __restrict__ Ws, const float* __restrict__ Wh,
                        float* __restrict__ q4, float* __restrict__ e4,
                        const int* __restrict__ lens) {
  __shared__ short As[128][72];  // bf16 A-tile chunk [m][k], +8 pad
  __shared__ short Bs[128][72];  // bf16 W-tile chunk [n][k], +8 pad
  const int tid = threadIdx.x;
  int blk = blockIdx.x;
  const bool isE = blk >= QBLK;
  if (isE) blk -= QBLK;
  const int bx = blk & 3, by = blk >> 2;
  const int row0 = by * 128, col0 = bx * 128;
  const float* A = isE ? enc : query;
  const float* W = isE ? Wh : Ws;
  if (isE && (row0 % S) >= lens[row0 / S]) return;  // fully-masked s-tile

  const int lr = tid >> 4;        // 0..15 (row group for staging)
  const int lc = (tid & 15) * 4;  // 0..60 (k cols for staging)
  const int lane = tid & 63, wv = tid >> 6;
  const int wm = (wv >> 1) * 64, wn = (wv & 1) * 64;
  const int lrow = lane & 15, lkg = (lane >> 4) * 8;

  f32x4 acc[4][4] = {};
  for (int k0 = 0; k0 < H; k0 += 64) {
    __syncthreads();
#pragma unroll
    for (int u = 0; u < 8; ++u) {
      int r = lr + u * 16;
      float4 av = *(const float4*)&A[(size_t)(row0 + r) * H + k0 + lc];
      *(uint2*)&As[r][lc] = make_uint2(pack_bf16(av.x, av.y), pack_bf16(av.z, av.w));
      float4 wv4 = *(const float4*)&W[(size_t)(col0 + r) * H + k0 + lc];
      *(uint2*)&Bs[r][lc] = make_uint2(pack_bf16(wv4.x, wv4.y), pack_bf16(wv4.z, wv4.w));
    }
    __syncthreads();
#pragma unroll
    for (int ks = 0; ks < 64; ks += 32) {
      bf16x8 af[4], bfr[4];
#pragma unroll
      for (int i = 0; i < 4; ++i) {
        af[i] = *(const bf16x8*)&As[wm + i * 16 + lrow][ks + lkg];
        bfr[i] = *(const bf16x8*)&Bs[wn + i * 16 + lrow][ks + lkg];
      }
#pragma unroll
      for (int mt = 0; mt < 4; ++mt)
#pragma unroll
        for (int nt = 0; nt < 4; ++nt)
          acc[mt][nt] = __builtin_amdgcn_mfma_f32_16x16x32_bf16(
              af[mt], bfr[nt], acc[mt][nt], 0, 0, 0);
    }
  }

  // Epilogue: C frag layout col=lane&15, row=(lane>>4)*4+reg (m89-verified).
  const int crow = (lane >> 4) * 4, ccol = lane & 15;
  if (!isE) {
    const int b = row0 / T;
#pragma unroll
    for (int mt = 0; mt < 4; ++mt) {
      const int m = (row0 % T) + wm + mt * 16 + crow;  // multiple of 4
      const int tile_t = m >> 2;
#pragma unroll
      for (int nt = 0; nt < 4; ++nt) {
        const int n = col0 + wn + nt * 16 + ccol;
        float* base = q4 + (size_t)b * T * H + (size_t)tile_t * (4 * H) +
                      (n >> 2) * 16 + (n & 3);
        f32x4 a = acc[mt][nt];
#pragma unroll
        for (int reg = 0; reg < 4; ++reg) base[reg * 4] = exp2c(C2LOG2E * a[reg]);
      }
    }
  } else {
    const int b = row0 / S;
#pragma unroll
    for (int mt = 0; mt < 4; ++mt) {
      const int s0 = (row0 % S) + wm + mt * 16 + crow;
#pragma unroll
      for (int nt = 0; nt < 4; ++nt) {
        const int n = col0 + wn + nt * 16 + ccol;
        float* base = e4 + (size_t)b * H * S + (size_t)(n >> 2) * (4 * S) +
                      (size_t)s0 * 4 + (n & 3);
        f32x4 a = acc[mt][nt];
#pragma unroll
        for (int reg = 0; reg < 4; ++reg) base[reg * 4] = exp2c(C2LOG2E * a[reg]);
      }
    }
  }
}

// acc += sum over 8 h of v/(1+q*e): two 4-trees merged, ONE rcp per 8 elems.
DEVI void tree8(float& acc, vf4 qa, vf4 qb, vf4 va, vf4 vb, vf4 ea, vf4 eb) {
  float a0 = __builtin_fmaf(qa[0], ea[0], 1.0f);
  float a1 = __builtin_fmaf(qa[1], ea[1], 1.0f);
  float a2 = __builtin_fmaf(qa[2], ea[2], 1.0f);
  float a3 = __builtin_fmaf(qa[3], ea[3], 1.0f);
  float b0 = __builtin_fmaf(qb[0], eb[0], 1.0f);
  float b1 = __builtin_fmaf(qb[1], eb[1], 1.0f);
  float b2 = __builtin_fmaf(qb[2], eb[2], 1.0f);
  float b3 = __builtin_fmaf(qb[3], eb[3], 1.0f);
  float dA01 = a0 * a1, dA23 = a2 * a3;
  float dB01 = b0 * b1, dB23 = b2 * b3;
  float nA01 = __builtin_fmaf(va[1], a0, va[0] * a1);
  float nA23 = __builtin_fmaf(va[3], a2, va[2] * a3);
  float nB01 = __builtin_fmaf(vb[1], b0, vb[0] * b1);
  float nB23 = __builtin_fmaf(vb[3], b2, vb[2] * b3);
  float dA = dA01 * dA23, dB = dB01 * dB23;
  float nA = __builtin_fmaf(nA23, dA01, nA01 * dA23);
  float nB = __builtin_fmaf(nB23, dB01, nB01 * dB23);
  float D = dA * dB;
  float N = __builtin_fmaf(nA, dB, nB * dA);
  acc = __builtin_fmaf(N, __builtin_amdgcn_rcpf(D), acc);
}

DEVI vf4 qload4(const ushort_t (&s_q4)[32][64], int h4q, int t) {
  uint2 qu = *(const uint2*)&s_q4[h4q][t * 4];
  vf4 q = {bf_lo(qu.x), bf_hi(qu.x), bf_lo(qu.y), bf_hi(qu.y)};
  return q;
}

// Stage one h-quarter (32 h4 rows x 16 t) of Q into the 4KB buffer.
DEVI void stage_quarter(ushort_t (&s_q4)[32][64], const vf4* __restrict__ qsrc,
                        int qt, int tid) {
  __syncthreads();  // previous-quarter reads done (uniform across waves)
#pragma unroll
  for (int u = 0; u < 2; ++u) {
    int g = tid + u * 256;                 // 0..511
    int tile = g >> 7, rem = g & 127;
    int h4q = rem >> 2, i = rem & 3;
    vf4 qv = qsrc[tile * 512 + (qt * 32 + h4q) * 4 + i];
    uint2 pk = make_uint2(pack_bf16(qv[0], qv[1]), pack_bf16(qv[2], qv[3]));
    ((uint2*)&s_q4[0][0])[h4q * 16 + tile * 4 + i] = pk;
  }
  __syncthreads();
}

// Bulk: NSIM strips (at strip indices wv+4*(ks0+r)) x 16 t; tree8 per h-pair.
template <int NSIM>
DEVI void passN16(ushort_t (&s_q4)[32][64], const vf4* __restrict__ qsrc,
                  const float* __restrict__ v, const float* __restrict__ e4b,
                  ushort_t (&s_sc16)[TT][SP], int ks0, int wv, int lane) {
  const int tid = wv * 64 + lane;
  float acc[NSIM][TT];
#pragma unroll
  for (int r = 0; r < NSIM; ++r)
#pragma unroll
    for (int t = 0; t < TT; ++t) acc[r][t] = 0.f;
  const float* ep = e4b + (size_t)(wv * 64 + lane) * 4 + (size_t)ks0 * 1024;
  for (int qt = 0; qt < 4; ++qt) {
    stage_quarter(s_q4, qsrc, qt, tid);
    for (int g = 0; g < 16; ++g) {     // h-pair within quarter
      const int h4 = qt * 32 + 2 * g;
      vf4 ea[NSIM], eb[NSIM];
#pragma unroll
      for (int r = 0; r < NSIM; ++r) {
        ea[r] = *(const vf4*)(ep + (size_t)h4 * (S * 4) + r * 1024);
        eb[r] = *(const vf4*)(ep + (size_t)(h4 + 1) * (S * 4) + r * 1024);
      }
      vf4 va = *(const vf4*)(v + h4 * 4);       // wave-uniform -> s_load
      vf4 vb = *(const vf4*)(v + h4 * 4 + 4);
#pragma unroll
      for (int t = 0; t < TT; ++t) {
        vf4 qa = qload4(s_q4, 2 * g, t);
        vf4 qb = qload4(s_q4, 2 * g + 1, t);
#pragma unroll
        for (int r = 0; r < NSIM; ++r)
          tree8(acc[r][t], qa, qb, va, vb, ea[r], eb[r]);
      }
    }
  }
#pragma unroll
  for (int r = 0; r < NSIM; ++r) {
    const int s = (wv + 4 * (ks0 + r)) * 64 + lane;
#pragma unroll
    for (int t = 0; t < TT; ++t) s_sc16[t][s] = to_bf16u(acc[r][t]);
  }
}

// Tail: R consecutive strips, wave computes rows {wv, wv+4, wv+8, wv+12}.
template <int R>
DEVI void passTail16(ushort_t (&s_q4)[32][64], const vf4* __restrict__ qsrc,
                     const float* __restrict__ v, const float* __restrict__ e4b,
                     ushort_t (&s_sc16)[TT][SP], int kbase, int wv, int lane) {
  const int tid = wv * 64 + lane;
  float acc[R][4];
#pragma unroll
  for (int r = 0; r < R; ++r)
#pragma unroll
    for (int jj = 0; jj < 4; ++jj) acc[r][jj] = 0.f;
  const float* ep = e4b + (size_t)(kbase * 64 + lane) * 4;
  for (int qt = 0; qt < 4; ++qt) {
    stage_quarter(s_q4, qsrc, qt, tid);
    for (int g = 0; g < 16; ++g) {
      const int h4 = qt * 32 + 2 * g;
      vf4 va = *(const vf4*)(v + h4 * 4);
      vf4 vb = *(const vf4*)(v + h4 * 4 + 4);
      vf4 ea[R], eb[R];
#pragma unroll
      for (int r = 0; r < R; ++r) {
        ea[r] = *(const vf4*)(ep + (size_t)h4 * (S * 4) + r * 256);
        eb[r] = *(const vf4*)(ep + (size_t)(h4 + 1) * (S * 4) + r * 256);
      }
#pragma unroll
      for (int jj = 0; jj < 4; ++jj) {
        vf4 qa = qload4(s_q4, 2 * g, wv + 4 * jj);
        vf4 qb = qload4(s_q4, 2 * g + 1, wv + 4 * jj);
#pragma unroll
        for (int r = 0; r < R; ++r)
          tree8(acc[r][jj], qa, qb, va, vb, ea[r], eb[r]);
      }
    }
  }
#pragma unroll
  for (int r = 0; r < R; ++r)
#pragma unroll
    for (int jj = 0; jj < 4; ++jj)
      s_sc16[wv + 4 * jj][(kbase + r) * 64 + lane] = to_bf16u(acc[r][jj]);
}

// Fused: scores -> masked softmax -> context. One block = (b, 16 timesteps).
__global__ __launch_bounds__(256, 4)
void attn_fused_kernel(const float* __restrict__ wsq, const float* __restrict__ wheT,
                       const float* __restrict__ enc, const float* __restrict__ v,
                       const int* __restrict__ lens, float* __restrict__ out) {
  __shared__ __align__(16) ushort_t s_sc16[TT][SP];  // 33 KB bf16 scores -> p
  __shared__ __align__(16) ushort_t s_q4[32][64];    // 4 KB bf16 Q quarter
  __shared__ long long s_w[32];
  __shared__ int s_bsel;

  const int tid = threadIdx.x;
  const int xcd = blockIdx.x & 7;     // dispatch round-robin heuristic
  const int j = blockIdx.x >> 3;      // 0..127
  const int slot = j >> 5;            // 0..3: which of this XCD's 4 batches
  const int tt = j & 31;              // 0..31 t-tile within batch

  // Runtime snake load-balance: rank batches by len (desc), XCD x gets ranks
  // {x, 15-x, 16+x, 31-x} -> balanced work, batch-major locality.
  if (tid < 32) s_w[tid] = ((long long)lens[tid] << 8) + tid;  // unique key
  __syncthreads();
  if (tid < 32) {
    long long wb = s_w[tid];
    int rank = 0;
#pragma unroll
    for (int b2 = 0; b2 < 32; ++b2) rank += (s_w[b2] > wb);
    int myrank = slot * 8 + ((slot & 1) ? (7 - xcd) : xcd);
    if (rank == myrank) s_bsel = tid;
  }
  __syncthreads();
  const int b = __builtin_amdgcn_readfirstlane(s_bsel);
  const int len = lens[b];

  // ---- Phase A: balanced strip schedule; bulk in NSIM<=2 chunks + tail ----
  {
    const int wv = tid >> 6, lane = tid & 63;
    const int NS = (len + 63) >> 6;  // 1..16 strips
    const int nsw = NS >> 2;         // bulk strips per wave (0..4)
    const int R = NS & 3;            // tail strips (0..3)
    const float* e4b = wheT + (size_t)b * H * S;  // [h4][s][4]
    const vf4* qsrc = (const vf4*)(wsq + (size_t)b * T * H + (size_t)tt * (TT * H));
    int k0 = 0;
    for (; k0 + 2 <= nsw; k0 += 2)
      passN16<2>(s_q4, qsrc, v, e4b, s_sc16, k0, wv, lane);
    if (k0 < nsw)
      passN16<1>(s_q4, qsrc, v, e4b, s_sc16, k0, wv, lane);
    switch (R) {
      case 1: passTail16<1>(s_q4, qsrc, v, e4b, s_sc16, nsw * 4, wv, lane); break;
      case 2: passTail16<2>(s_q4, qsrc, v, e4b, s_sc16, nsw * 4, wv, lane); break;
      case 3: passTail16<3>(s_q4, qsrc, v, e4b, s_sc16, nsw * 4, wv, lane); break;
      default: break;
    }
  }
  __syncthreads();

  // ---- Phase B: softmax WITHOUT max-shift; p = exp2(-2*log2e * acc);
  // store NORMALIZED p (bf16). Wave w: rows {w, w+4, w+8, w+12}. ----
  {
    const int wv = tid >> 6, lane = tid & 63;
#pragma unroll
    for (int jj = 0; jj < 4; ++jj) {
      const int tr = wv + 4 * jj;
      float ps[S / 64];
      float sum = 0.f;
#pragma unroll
      for (int i = 0; i < S / 64; ++i) {
        int s = lane + 64 * i;
        float sc = bf_one(s_sc16[tr][s]);
        float p = (s < len) ? __builtin_amdgcn_exp2f(sc * -C2LOG2E) : 0.f;
        ps[i] = p;
        sum += p;
      }
#pragma unroll
      for (int o = 1; o < 64; o <<= 1) sum += __shfl_xor(sum, o, 64);
      float rs = 1.0f / sum;
#pragma unroll
      for (int i = 0; i < S / 64; ++i) {
        float pn = ps[i] * rs;
        s_sc16[tr][lane + 64 * i] = to_bf16u(pn);
        if (tt == T / TT - 1 && tr == TT - 1)  // last timestep: attn weights
          out[(size_t)B * T * H + (size_t)b * S + lane + 64 * i] = pn;
      }
    }
  }
  __syncthreads();

  // ---- Phase C on MFMA: ctx[16t][512h] = P[16xS] * enc[Sx512]. ----
  {
    const int wv = tid >> 6, lane = tid & 63;
    const int lrow = lane & 15, lkg = (lane >> 4) * 8;
    const int hbase = wv * 128;
    const float* encb = enc + (size_t)b * S * H;
    f32x4 acc[8] = {};
    const int nch = (len + 31) >> 5;  // k-chunks of 32 s (P==0 beyond len)
    for (int kc = 0; kc < nch; ++kc) {
      const int k0 = kc * 32 + lkg;
      bf16x8 pa = *(const bf16x8*)&s_sc16[lrow][k0];
#pragma unroll
      for (int nt = 0; nt < 8; ++nt) {
        const int h = hbase + nt * 16 + lrow;
        const float* ep = encb + (size_t)k0 * H + h;
        float b0 = ep[0 * H], b1 = ep[1 * H], b2 = ep[2 * H], b3 = ep[3 * H];
        float b4 = ep[4 * H], b5 = ep[5 * H], b6 = ep[6 * H], b7 = ep[7 * H];
        uint4 uu = make_uint4(pack_bf16(b0, b1), pack_bf16(b2, b3),
                              pack_bf16(b4, b5), pack_bf16(b6, b7));
        bf16x8 bfr = __builtin_bit_cast(bf16x8, uu);
        acc[nt] = __builtin_amdgcn_mfma_f32_16x16x32_bf16(pa, bfr, acc[nt], 0, 0, 0);
      }
    }
    const int crow = (lane >> 4) * 4, ccol = lane & 15;
#pragma unroll
    for (int nt = 0; nt < 8; ++nt) {
      const int h = hbase + nt * 16 + ccol;
#pragma unroll
      for (int reg = 0; reg < 4; ++reg) {
        const int t = crow + reg;
        out[((size_t)b * T + tt * TT + t) * H + h] = acc[nt][reg];
      }
    }
  }
}

extern "C" void kernel_launch(void* const* d_in, const int* in_sizes, int n_in,
                              void* d_out, int out_size, void* d_ws, size_t ws_size,
                              hipStream_t stream) {
  const float* query = (const float*)d_in[0];  // [B,T,H]
  const float* enc   = (const float*)d_in[1];  // [B,S,H]
  const int*   lens  = (const int*)d_in[2];    // [B]
  const float* Ws    = (const float*)d_in[3];  // [H,H]
  const float* Wh    = (const float*)d_in[4];  // [H,H]
  const float* v     = (const float*)d_in[5];  // [H]
  float* out = (float*)d_out;
  float* wsq  = (float*)d_ws;                  // Q4 [B,T/4,H/4,4,4]
  float* wheT = wsq + (size_t)B * T * H;       // E4 [B,H/4,S,4]

  mfma_matmul_kernel<<<dim3(QBLK + EBLK), 256, 0, stream>>>(query, enc, Ws, Wh, wsq, wheT, lens);
  attn_fused_kernel<<<dim3(B * (T / TT)), 256, 0, stream>>>(wsq, wheT, enc, v, lens, out);
}